// Round 3
// baseline (2080.101 us; speedup 1.0000x reference)
//
#include <hip/hip_runtime.h>
#include <hip/hip_bf16.h>
#include <math.h>

// B=4096 queries, D=256, K=65536 centroids (f32).
// Round 3: 1-term (hi) MFMA filter scan at 4 blocks/CU -> chunk survivors ->
// sparse 3-term (f16x2 split) MFMA rescore on survivors -> exact f32 finalize.

#define DDIM 256
#define NCH 32          // chunks
#define CHSZ 2048       // centroids per chunk
#define F16_MINN 6.103515625e-5f

typedef __attribute__((ext_vector_type(8))) _Float16 half8;
typedef __attribute__((ext_vector_type(4))) _Float16 half4;
typedef __attribute__((ext_vector_type(4))) float f32x4;

__device__ __forceinline__ void gl_lds16(const void* g, void* l) {
  __builtin_amdgcn_global_load_lds((const __attribute__((address_space(1))) void*)g,
                                   (__attribute__((address_space(3))) void*)l, 16, 0, 0);
}

// ---------------- ctl init: [0..31]=cnt per chunk, [32]=cmax_sq bits, [33]=xmax_sq bits --
__global__ void initctl_kernel(unsigned* __restrict__ ctl) {
  if (threadIdx.x < 64) ctl[threadIdx.x] = 0u;
}

// ---------------- split centroids: f32 -> (h0, h1*2048) ----------------
__global__ __launch_bounds__(256) void split_kernel(const float* __restrict__ in,
                                                    _Float16* __restrict__ o0,
                                                    _Float16* __restrict__ o1, int n4) {
  int i = blockIdx.x * 256 + threadIdx.x;
  if (i >= n4) return;
  float4 v = ((const float4*)in)[i];
  float vv[4] = {v.x, v.y, v.z, v.w};
  half4 h0, h1;
#pragma unroll
  for (int e = 0; e < 4; ++e) {
    float xx = vv[e];
    _Float16 a = (fabsf(xx) < F16_MINN) ? (_Float16)0.f : (_Float16)xx;
    float r = (xx - (float)a) * 2048.0f;
    h0[e] = a;
    h1[e] = (_Float16)r;
  }
  *(half4*)(o0 + (size_t)i * 4) = h0;
  *(half4*)(o1 + (size_t)i * 4) = h1;
}

// ---------------- split x: hi part only ----------------
__global__ __launch_bounds__(256) void splitx_kernel(const float* __restrict__ in,
                                                     _Float16* __restrict__ o0, int n4) {
  int i = blockIdx.x * 256 + threadIdx.x;
  if (i >= n4) return;
  float4 v = ((const float4*)in)[i];
  float vv[4] = {v.x, v.y, v.z, v.w};
  half4 h0;
#pragma unroll
  for (int e = 0; e < 4; ++e)
    h0[e] = (fabsf(vv[e]) < F16_MINN) ? (_Float16)0.f : (_Float16)vv[e];
  *(half4*)(o0 + (size_t)i * 4) = h0;
}

// ---------------- c_sq + max ||c||^2 ----------------
__global__ __launch_bounds__(256) void csq_kernel(const float* __restrict__ cent,
                                                  float* __restrict__ c_sq,
                                                  unsigned* __restrict__ ctl) {
  int gtid = blockIdx.x * 256 + threadIdx.x;
  int c = gtid >> 6;
  int lane = threadIdx.x & 63;
  float4 v = ((const float4*)(cent + (size_t)c * DDIM))[lane];
  float s = v.x * v.x + v.y * v.y + v.z * v.z + v.w * v.w;
#pragma unroll
  for (int off = 32; off > 0; off >>= 1) s += __shfl_down(s, off, 64);
  if (lane == 0) {
    c_sq[c] = s;
    atomicMax(&ctl[32], __float_as_uint(s));   // positive floats: uint order == float order
  }
}

// ---------------- max ||x||^2 ----------------
__global__ __launch_bounds__(256) void xnmax_kernel(const float* __restrict__ x,
                                                    unsigned* __restrict__ ctl) {
  int gtid = blockIdx.x * 256 + threadIdx.x;
  int q = gtid >> 6;
  int lane = threadIdx.x & 63;
  float4 v = ((const float4*)(x + (size_t)q * DDIM))[lane];
  float s = v.x * v.x + v.y * v.y + v.z * v.z + v.w * v.w;
#pragma unroll
  for (int off = 32; off > 0; off >>= 1) s += __shfl_down(s, off, 64);
  if (lane == 0) atomicMax(&ctl[33], __float_as_uint(s));
}

// ---------------- Phase A: hi-only MFMA scan, per-(q,chunk) min d_hi ----------------
// Grid (32 qb, 32 kc). Block 128q x 128c subtile, ct=16 over 2048-c chunk.
// acc = 64 f32/lane -> 4 blocks/CU.
__global__ __launch_bounds__(256, 4) void phaseA_kernel(
    const _Float16* __restrict__ x0, const _Float16* __restrict__ c0,
    const float* __restrict__ c_sq, float* __restrict__ dm) {
  __shared__ __align__(16) _Float16 As0[4096], Bs0[4096];
  __shared__ float rd[2][128];
  const int qb = blockIdx.x, kc = blockIdx.y;
  const int tid = (int)threadIdx.x;
  const int lane = tid & 63, w = tid >> 6;
  const int mh = w >> 1, nh = w & 1;
  const int col = lane & 15, quad = lane >> 4;
  const int qrow0 = qb * 128;

  float bestd[4][4];
#pragma unroll
  for (int mt = 0; mt < 4; ++mt)
#pragma unroll
    for (int rg = 0; rg < 4; ++rg) bestd[mt][rg] = INFINITY;

  for (int ct = 0; ct < CHSZ / 128; ++ct) {
    const int cbase = kc * CHSZ + ct * 128;
    f32x4 hi[4][4];
#pragma unroll
    for (int mt = 0; mt < 4; ++mt)
#pragma unroll
      for (int nt = 0; nt < 4; ++nt) hi[mt][nt] = (f32x4)0.0f;

    for (int kt = 0; kt < 8; ++kt) {
      const int k0 = kt * 32;
      __syncthreads();
#pragma unroll
      for (int i = 0; i < 2; ++i) {
        int u = i * 256 + tid;
        int s = u >> 6, q = (u >> 4) & 3, r = u & 15;
        gl_lds16(x0 + (size_t)(qrow0 + s * 16 + r) * DDIM + k0 + q * 8, As0 + (size_t)u * 8);
        gl_lds16(c0 + (size_t)(cbase + s * 16 + r) * DDIM + k0 + q * 8, Bs0 + (size_t)u * 8);
      }
      __syncthreads();
      half8 b0f[4];
#pragma unroll
      for (int nt = 0; nt < 4; ++nt)
        b0f[nt] = *(const half8*)(Bs0 + (((nh * 4 + nt) * 4 + quad) * 16 + col) * 8);
#pragma unroll
      for (int mt = 0; mt < 4; ++mt) {
        half8 a0f = *(const half8*)(As0 + (((mh * 4 + mt) * 4 + quad) * 16 + col) * 8);
#pragma unroll
        for (int nt = 0; nt < 4; ++nt)
          hi[mt][nt] = __builtin_amdgcn_mfma_f32_16x16x32_f16(a0f, b0f[nt], hi[mt][nt], 0, 0, 0);
      }
    }
#pragma unroll
    for (int nt = 0; nt < 4; ++nt) {
      int cidx = cbase + (nh * 4 + nt) * 16 + col;
      float cs = c_sq[cidx];
#pragma unroll
      for (int mt = 0; mt < 4; ++mt)
#pragma unroll
        for (int rg = 0; rg < 4; ++rg)
          bestd[mt][rg] = fminf(bestd[mt][rg], fmaf(-2.0f, hi[mt][nt][rg], cs));
    }
  }
#pragma unroll
  for (int mt = 0; mt < 4; ++mt)
#pragma unroll
    for (int rg = 0; rg < 4; ++rg) {
      float d = bestd[mt][rg];
#pragma unroll
      for (int off = 1; off < 16; off <<= 1) d = fminf(d, __shfl_xor(d, off, 64));
      if (col == 0) rd[nh][mh * 64 + mt * 16 + quad * 4 + rg] = d;
    }
  __syncthreads();
  if (tid < 128)
    dm[(size_t)(qrow0 + tid) * NCH + kc] = fminf(rd[0][tid], rd[1][tid]);
}

// ---------------- survivors: threshold + per-chunk query lists + pk init ----------------
__global__ __launch_bounds__(256) void survivors_kernel(
    const float* __restrict__ dm, unsigned* __restrict__ ctl,
    unsigned short* __restrict__ qlist, unsigned long long* __restrict__ pk) {
  int q = blockIdx.x * 256 + threadIdx.x;
  float M = INFINITY;
#pragma unroll
  for (int j = 0; j < NCH; ++j) M = fminf(M, dm[(size_t)q * NCH + j]);
  float cmaxsq = __uint_as_float(ctl[32]);
  float xmaxsq = __uint_as_float(ctl[33]);
  // |d - d_hi| <= ~2^-10 * ||x|| * ||c|| + slop; margin = 2E with >=4x safety
  float T = M + sqrtf(cmaxsq * xmaxsq) * (1.0f / 128.0f) + 1.0f;
#pragma unroll
  for (int j = 0; j < NCH; ++j) {
    pk[(size_t)q * NCH + j] = 0xFFFFFFFFFFFFFFFFull;
    if (dm[(size_t)q * NCH + j] <= T) {
      unsigned pos = atomicAdd(&ctl[j], 1u);
      qlist[j * 4096 + pos] = (unsigned short)q;
    }
  }
}

// ---------------- Phase B: 3-term MFMA on gathered survivors ----------------
// Grid (t=32, j=32, cr=8). Block: 128 gathered queries x 256 centroids (ct=2 x 128).
__global__ __launch_bounds__(256, 2) void phaseB_kernel(
    const float* __restrict__ x, const _Float16* __restrict__ x0,
    const _Float16* __restrict__ c0, const _Float16* __restrict__ c1,
    const float* __restrict__ c_sq, const unsigned* __restrict__ ctl,
    const unsigned short* __restrict__ qlist,
    unsigned long long* __restrict__ pk) {
  __shared__ __align__(16) _Float16 As0[4096], As1[4096], Bs0[4096], Bs1[4096];
  __shared__ float rd[2][128];
  __shared__ int ri[2][128];
  __shared__ unsigned short qids[128];

  const int t = blockIdx.x, j = blockIdx.y, cr = blockIdx.z;
  const int cnt = (int)ctl[j];
  if (t * 128 >= cnt) return;
  const int tid = (int)threadIdx.x;
  const int Q = min(128, cnt - t * 128);
  if (tid < 128) {
    int pos = t * 128 + tid;
    qids[tid] = (pos < cnt) ? qlist[j * 4096 + pos] : qlist[j * 4096];
  }
  const int lane = tid & 63, w = tid >> 6;
  const int mh = w >> 1, nh = w & 1;
  const int col = lane & 15, quad = lane >> 4;

  float bestd[4][4];
  int besti[4][4];
#pragma unroll
  for (int mt = 0; mt < 4; ++mt)
#pragma unroll
    for (int rg = 0; rg < 4; ++rg) { bestd[mt][rg] = INFINITY; besti[mt][rg] = 0x7fffffff; }

  for (int ct = 0; ct < 2; ++ct) {
    const int cbase = j * CHSZ + cr * 256 + ct * 128;
    f32x4 hi[4][4], lo[4][4];
#pragma unroll
    for (int mt = 0; mt < 4; ++mt)
#pragma unroll
      for (int nt = 0; nt < 4; ++nt) { hi[mt][nt] = (f32x4)0.0f; lo[mt][nt] = (f32x4)0.0f; }

    for (int kt = 0; kt < 8; ++kt) {
      const int k0 = kt * 32;
      __syncthreads();   // also orders qids store before first A-gather read
#pragma unroll
      for (int i = 0; i < 2; ++i) {
        int u = i * 256 + tid;
        int s = u >> 6, q = (u >> 4) & 3, r = u & 15;
        size_t brow = (size_t)(cbase + s * 16 + r) * DDIM + k0 + q * 8;
        gl_lds16(c0 + brow, Bs0 + (size_t)u * 8);
        gl_lds16(c1 + brow, Bs1 + (size_t)u * 8);
      }
#pragma unroll
      for (int i = 0; i < 2; ++i) {
        int u = i * 256 + tid;
        int s = u >> 6, q = (u >> 4) & 3, r = u & 15;
        int qrow = (int)qids[s * 16 + r];
        size_t abase = (size_t)qrow * DDIM + k0 + q * 8;
        half8 h0 = *(const half8*)(x0 + abase);
        float4 f0 = *(const float4*)(x + abase);
        float4 f1 = *(const float4*)(x + abase + 4);
        float ff[8] = {f0.x, f0.y, f0.z, f0.w, f1.x, f1.y, f1.z, f1.w};
        half8 h1;
#pragma unroll
        for (int e = 0; e < 8; ++e) h1[e] = (_Float16)((ff[e] - (float)h0[e]) * 2048.0f);
        *(half8*)(As0 + (size_t)u * 8) = h0;
        *(half8*)(As1 + (size_t)u * 8) = h1;
      }
      __syncthreads();
      half8 b0f[4], b1f[4];
#pragma unroll
      for (int nt = 0; nt < 4; ++nt) {
        int off = (((nh * 4 + nt) * 4 + quad) * 16 + col) * 8;
        b0f[nt] = *(const half8*)(Bs0 + off);
        b1f[nt] = *(const half8*)(Bs1 + off);
      }
#pragma unroll
      for (int mt = 0; mt < 4; ++mt) {
        int off = (((mh * 4 + mt) * 4 + quad) * 16 + col) * 8;
        half8 a0f = *(const half8*)(As0 + off);
        half8 a1f = *(const half8*)(As1 + off);
#pragma unroll
        for (int nt = 0; nt < 4; ++nt) {
          hi[mt][nt] = __builtin_amdgcn_mfma_f32_16x16x32_f16(a0f, b0f[nt], hi[mt][nt], 0, 0, 0);
          lo[mt][nt] = __builtin_amdgcn_mfma_f32_16x16x32_f16(a0f, b1f[nt], lo[mt][nt], 0, 0, 0);
          lo[mt][nt] = __builtin_amdgcn_mfma_f32_16x16x32_f16(a1f, b0f[nt], lo[mt][nt], 0, 0, 0);
        }
      }
    }
#pragma unroll
    for (int nt = 0; nt < 4; ++nt) {
      int cidx = cbase + (nh * 4 + nt) * 16 + col;
      float cs = c_sq[cidx];
#pragma unroll
      for (int mt = 0; mt < 4; ++mt)
#pragma unroll
        for (int rg = 0; rg < 4; ++rg) {
          float dot = hi[mt][nt][rg] + lo[mt][nt][rg] * (1.0f / 2048.0f);
          float d = fmaf(-2.0f, dot, cs);
          if (d < bestd[mt][rg] || (d == bestd[mt][rg] && cidx < besti[mt][rg])) {
            bestd[mt][rg] = d; besti[mt][rg] = cidx;
          }
        }
    }
  }
#pragma unroll
  for (int mt = 0; mt < 4; ++mt)
#pragma unroll
    for (int rg = 0; rg < 4; ++rg) {
      float d = bestd[mt][rg]; int ix = besti[mt][rg];
#pragma unroll
      for (int off = 1; off < 16; off <<= 1) {
        float od = __shfl_xor(d, off, 64);
        int oi = __shfl_xor(ix, off, 64);
        if (od < d || (od == d && oi < ix)) { d = od; ix = oi; }
      }
      if (col == 0) {
        int row = mh * 64 + mt * 16 + quad * 4 + rg;
        rd[nh][row] = d; ri[nh][row] = ix;
      }
    }
  __syncthreads();
  if (tid < Q) {
    float d0 = rd[0][tid]; int i0 = ri[0][tid];
    float d1 = rd[1][tid]; int i1 = ri[1][tid];
    if (d1 < d0 || (d1 == d0 && i1 < i0)) { d0 = d1; i0 = i1; }
    // d0 + 1024 > 0 always (d >= -2*||x||max*||c||max > -1024) -> uint bits monotone
    unsigned long long p =
        ((unsigned long long)__float_as_uint(d0 + 1024.0f) << 32) | (unsigned)i0;
    atomicMin(&pk[(size_t)qids[tid] * NCH + j], p);
  }
}

// ---------------- finalize: exact f32 rescore of surviving chunk winners ----------------
__global__ __launch_bounds__(256) void finalize_kernel(
    const unsigned long long* __restrict__ pk, const float* __restrict__ x,
    const float* __restrict__ cent, const float* __restrict__ c_sq,
    float* __restrict__ out) {
  int q = blockIdx.x * 4 + ((int)threadIdx.x >> 6);
  int lane = (int)threadIdx.x & 63;
  float4 xv = ((const float4*)x)[(size_t)q * 64 + lane];
  float bd = INFINITY; int bi = 0x7fffffff;
  for (int p = 0; p < NCH; ++p) {
    unsigned long long e = pk[(size_t)q * NCH + p];
    if (e == 0xFFFFFFFFFFFFFFFFull) continue;
    int idx = (int)(unsigned)(e & 0xFFFFFFFFu);
    float4 cv = ((const float4*)cent)[(size_t)idx * 64 + lane];
    float s = xv.x * cv.x + xv.y * cv.y + xv.z * cv.z + xv.w * cv.w;
#pragma unroll
    for (int off = 32; off > 0; off >>= 1) s += __shfl_down(s, off, 64);
    s = __shfl(s, 0, 64);
    float d = fmaf(-2.0f, s, c_sq[idx]);
    if (d < bd || (d == bd && idx < bi)) { bd = d; bi = idx; }
  }
  if (bi == 0x7fffffff) bi = 0;  // defensive; cannot happen (winner chunk always survives)
  float4 v = ((const float4*)cent)[(size_t)bi * 64 + lane];
  ((float4*)out)[(size_t)q * 64 + lane] = v;
  if (lane == 0) out[(size_t)4096 * DDIM + q] = (float)bi;
}

extern "C" void kernel_launch(void* const* d_in, const int* in_sizes, int n_in,
                              void* d_out, int out_size, void* d_ws, size_t ws_size,
                              hipStream_t stream) {
  const float* x = (const float*)d_in[1];     // [4096,256]
  const float* cent = (const float*)d_in[2];  // [65536,256]
  float* out = (float*)d_out;
  char* ws = (char*)d_ws;

  const size_t OFF_C0  = 0;          // 33,554,432
  const size_t OFF_C1  = 33554432;   // 33,554,432
  const size_t OFF_X0  = 67108864;   //  2,097,152
  const size_t OFF_CSQ = 69206016;   //    262,144
  const size_t OFF_CTL = 69468160;   //        256
  const size_t OFF_QL  = 69468416;   //    262,144  u16[32][4096]
  const size_t OFF_PK  = 69730560;   //  1,048,576  u64[4096][32]
  const size_t OFF_DM  = 70779136;   //    524,288  f32[4096][32]
  const size_t NEED    = 71303424;
  if (ws_size < NEED) return;  // harness ws verified >= 72,089,600 in round 2

  _Float16* c0 = (_Float16*)(ws + OFF_C0);
  _Float16* c1 = (_Float16*)(ws + OFF_C1);
  _Float16* x0 = (_Float16*)(ws + OFF_X0);
  float* c_sq = (float*)(ws + OFF_CSQ);
  unsigned* ctl = (unsigned*)(ws + OFF_CTL);
  unsigned short* qlist = (unsigned short*)(ws + OFF_QL);
  unsigned long long* pk = (unsigned long long*)(ws + OFF_PK);
  float* dm = (float*)(ws + OFF_DM);

  initctl_kernel<<<1, 64, 0, stream>>>(ctl);
  split_kernel<<<16384, 256, 0, stream>>>(cent, c0, c1, 65536 * 256 / 4);
  splitx_kernel<<<1024, 256, 0, stream>>>(x, x0, 4096 * 256 / 4);
  csq_kernel<<<16384, 256, 0, stream>>>(cent, c_sq, ctl);
  xnmax_kernel<<<1024, 256, 0, stream>>>(x, ctl);
  phaseA_kernel<<<dim3(32, 32), 256, 0, stream>>>(x0, c0, c_sq, dm);
  survivors_kernel<<<16, 256, 0, stream>>>(dm, ctl, qlist, pk);
  phaseB_kernel<<<dim3(32, 32, 8), 256, 0, stream>>>(x, x0, c0, c1, c_sq, ctl, qlist, pk);
  finalize_kernel<<<1024, 256, 0, stream>>>(pk, x, cent, c_sq, out);
}

// Round 4
// 776.639 us; speedup vs baseline: 2.6783x; 2.6783x over previous
//
#include <hip/hip_runtime.h>
#include <hip/hip_bf16.h>
#include <math.h>

// B=4096 queries, D=256, K=65536 centroids (f32).
// dists[b,k] = ||c_k||^2 - 2 x_b.c_k ; codes=argmin ; out0=centroids[codes], out1=codes.
// Round 4: round-2's exact f16x2-split 3-term MFMA kernel with BK=64 staging
// (half the barrier iterations). Sparse phaseA/B machinery removed (round-3 regression).

#define DDIM 256
#define NKC 16
#define KCHUNK 4096
#define F16_MINN 6.103515625e-5f

typedef __attribute__((ext_vector_type(8))) _Float16 half8;
typedef __attribute__((ext_vector_type(4))) _Float16 half4;
typedef __attribute__((ext_vector_type(4))) float f32x4;

__device__ __forceinline__ void gl_lds16(const void* g, void* l) {
  __builtin_amdgcn_global_load_lds((const __attribute__((address_space(1))) void*)g,
                                   (__attribute__((address_space(3))) void*)l, 16, 0, 0);
}

// ---------------- split: f32 -> (h0, h1*2048) f16 pair ----------------
__global__ __launch_bounds__(256) void split_kernel(const float* __restrict__ in,
                                                    _Float16* __restrict__ o0,
                                                    _Float16* __restrict__ o1, int n4) {
  int i = blockIdx.x * 256 + threadIdx.x;
  if (i >= n4) return;
  float4 v = ((const float4*)in)[i];
  float vv[4] = {v.x, v.y, v.z, v.w};
  half4 h0, h1;
#pragma unroll
  for (int e = 0; e < 4; ++e) {
    float x = vv[e];
    _Float16 a = (fabsf(x) < F16_MINN) ? (_Float16)0.f : (_Float16)x;
    float r = (x - (float)a) * 2048.0f;   // exact: cvt + Sterbenz sub + pow2 scale
    h0[e] = a;
    h1[e] = (_Float16)r;
  }
  *(half4*)(o0 + (size_t)i * 4) = h0;
  *(half4*)(o1 + (size_t)i * 4) = h1;
}

// ---------------- c_sq[k] = sum_d centroids[k][d]^2 (exact f32) ----------------
__global__ __launch_bounds__(256) void csq_kernel(const float* __restrict__ cent,
                                                  float* __restrict__ c_sq) {
  int gtid = blockIdx.x * 256 + threadIdx.x;
  int c = gtid >> 6;
  int lane = threadIdx.x & 63;
  float4 v = ((const float4*)(cent + (size_t)c * DDIM))[lane];
  float s = v.x * v.x + v.y * v.y + v.z * v.z + v.w * v.w;
#pragma unroll
  for (int off = 32; off > 0; off >>= 1) s += __shfl_down(s, off, 64);
  if (lane == 0) c_sq[c] = s;
}

// ---------------- MFMA distance + per-chunk argmin, BK=64 ----------------
// Grid (32, 16). Block: 128 queries x 4096 centroids (ct=32 subtiles of 128).
// LDS per split-buffer: 2 slabs x [8 subtiles][4 quads][16 rows][8 f16] = 8192 halfs.
__global__ __launch_bounds__(256, 2) void mfma_dist_kernel(
    const _Float16* __restrict__ x0, const _Float16* __restrict__ x1,
    const _Float16* __restrict__ c0, const _Float16* __restrict__ c1,
    const float* __restrict__ c_sq,
    float* __restrict__ part_d, int* __restrict__ part_i) {
  __shared__ __align__(16) _Float16 As0[8192], As1[8192], Bs0[8192], Bs1[8192];
  __shared__ float rd[2][128];
  __shared__ int   ri[2][128];

  const int qb = blockIdx.x, kc = blockIdx.y;
  const int tid = (int)threadIdx.x;
  const int lane = tid & 63, w = tid >> 6;
  const int mh = w >> 1, nh = w & 1;          // wave quadrant of the 128x128 tile
  const int col = lane & 15, quad = lane >> 4;
  const int qrow0 = qb * 128;

  float bestd[4][4];
  int   besti[4][4];
#pragma unroll
  for (int mt = 0; mt < 4; ++mt)
#pragma unroll
    for (int rg = 0; rg < 4; ++rg) { bestd[mt][rg] = INFINITY; besti[mt][rg] = 0x7fffffff; }

  for (int ct = 0; ct < 32; ++ct) {
    const int cbase = kc * KCHUNK + ct * 128;
    f32x4 hi[4][4], lo[4][4];
#pragma unroll
    for (int mt = 0; mt < 4; ++mt)
#pragma unroll
      for (int nt = 0; nt < 4; ++nt) { hi[mt][nt] = (f32x4)0.0f; lo[mt][nt] = (f32x4)0.0f; }

    for (int kto = 0; kto < 4; ++kto) {       // BK=64 per barrier pair
      __syncthreads();  // previous iteration's ds_reads drained
#pragma unroll
      for (int ksub = 0; ksub < 2; ++ksub) {
        const int k0 = kto * 64 + ksub * 32;
#pragma unroll
        for (int i = 0; i < 2; ++i) {
          int u = i * 256 + tid;              // 0..511
          int s = u >> 6, q = (u >> 4) & 3, r = u & 15;
          size_t arow = (size_t)(qrow0 + s * 16 + r) * DDIM + k0 + q * 8;
          size_t brow = (size_t)(cbase + s * 16 + r) * DDIM + k0 + q * 8;
          int ldso = ksub * 4096 + u * 8;
          gl_lds16(x0 + arow, As0 + ldso);
          gl_lds16(x1 + arow, As1 + ldso);
          gl_lds16(c0 + brow, Bs0 + ldso);
          gl_lds16(c1 + brow, Bs1 + ldso);
        }
      }
      __syncthreads();

#pragma unroll
      for (int ksub = 0; ksub < 2; ++ksub) {
        const int base = ksub * 4096;
        half8 b0f[4], b1f[4];
#pragma unroll
        for (int nt = 0; nt < 4; ++nt) {
          int off = base + (((nh * 4 + nt) * 4 + quad) * 16 + col) * 8;
          b0f[nt] = *(const half8*)(Bs0 + off);
          b1f[nt] = *(const half8*)(Bs1 + off);
        }
#pragma unroll
        for (int mt = 0; mt < 4; ++mt) {
          int off = base + (((mh * 4 + mt) * 4 + quad) * 16 + col) * 8;
          half8 a0f = *(const half8*)(As0 + off);
          half8 a1f = *(const half8*)(As1 + off);
#pragma unroll
          for (int nt = 0; nt < 4; ++nt) {
            hi[mt][nt] = __builtin_amdgcn_mfma_f32_16x16x32_f16(a0f, b0f[nt], hi[mt][nt], 0, 0, 0);
            lo[mt][nt] = __builtin_amdgcn_mfma_f32_16x16x32_f16(a0f, b1f[nt], lo[mt][nt], 0, 0, 0);
            lo[mt][nt] = __builtin_amdgcn_mfma_f32_16x16x32_f16(a1f, b0f[nt], lo[mt][nt], 0, 0, 0);
          }
        }
      }
    }
    // fold 128-wide subtile into running argmin (C layout: row=quad*4+rg, col=lane&15)
#pragma unroll
    for (int nt = 0; nt < 4; ++nt) {
      int cidx = cbase + (nh * 4 + nt) * 16 + col;
      float cs = c_sq[cidx];
#pragma unroll
      for (int mt = 0; mt < 4; ++mt)
#pragma unroll
        for (int rg = 0; rg < 4; ++rg) {
          float dot = hi[mt][nt][rg] + lo[mt][nt][rg] * (1.0f / 2048.0f);
          float d = fmaf(-2.0f, dot, cs);
          if (d < bestd[mt][rg] || (d == bestd[mt][rg] && cidx < besti[mt][rg])) {
            bestd[mt][rg] = d; besti[mt][rg] = cidx;
          }
        }
    }
  }

  // reduce across the 16 col-lanes holding each row
#pragma unroll
  for (int mt = 0; mt < 4; ++mt)
#pragma unroll
    for (int rg = 0; rg < 4; ++rg) {
      float d = bestd[mt][rg]; int ix = besti[mt][rg];
#pragma unroll
      for (int off = 1; off < 16; off <<= 1) {
        float od = __shfl_xor(d, off, 64);
        int   oi = __shfl_xor(ix, off, 64);
        if (od < d || (od == d && oi < ix)) { d = od; ix = oi; }
      }
      if (col == 0) {
        int row = mh * 64 + mt * 16 + quad * 4 + rg;
        rd[nh][row] = d; ri[nh][row] = ix;
      }
    }
  __syncthreads();
  if (tid < 128) {
    float d0 = rd[0][tid]; int i0 = ri[0][tid];
    float d1 = rd[1][tid]; int i1 = ri[1][tid];
    if (d1 < d0 || (d1 == d0 && i1 < i0)) { d0 = d1; i0 = i1; }
    int qg = qrow0 + tid;
    part_d[(size_t)qg * NKC + kc] = d0;
    part_i[(size_t)qg * NKC + kc] = i0;
  }
}

// ---------------- finalize: exact-f32 rescore of 16 chunk winners + gather ----------------
__global__ __launch_bounds__(256) void finalize_rescore(
    const int* __restrict__ part_i, const float* __restrict__ x,
    const float* __restrict__ cent, const float* __restrict__ c_sq,
    float* __restrict__ out) {
  int q = blockIdx.x * 4 + ((int)threadIdx.x >> 6);
  int lane = (int)threadIdx.x & 63;
  float4 xv = ((const float4*)x)[(size_t)q * 64 + lane];
  float bd = INFINITY; int bi = 0x7fffffff;
  for (int p = 0; p < NKC; ++p) {
    int idx = part_i[(size_t)q * NKC + p];
    float4 cv = ((const float4*)cent)[(size_t)idx * 64 + lane];
    float s = xv.x * cv.x + xv.y * cv.y + xv.z * cv.z + xv.w * cv.w;
#pragma unroll
    for (int off = 32; off > 0; off >>= 1) s += __shfl_down(s, off, 64);
    s = __shfl(s, 0, 64);
    float d = fmaf(-2.0f, s, c_sq[idx]);
    if (d < bd || (d == bd && idx < bi)) { bd = d; bi = idx; }
  }
  float4 v = ((const float4*)cent)[(size_t)bi * 64 + lane];
  ((float4*)out)[(size_t)q * 64 + lane] = v;
  if (lane == 0) out[(size_t)4096 * DDIM + q] = (float)bi;
}

extern "C" void kernel_launch(void* const* d_in, const int* in_sizes, int n_in,
                              void* d_out, int out_size, void* d_ws, size_t ws_size,
                              hipStream_t stream) {
  const float* x    = (const float*)d_in[1];   // [4096,256]
  const float* cent = (const float*)d_in[2];   // [65536,256]
  float* out = (float*)d_out;
  char* ws = (char*)d_ws;

  const size_t OFF_C0  = 0;
  const size_t OFF_C1  = 33554432;
  const size_t OFF_X0  = 67108864;
  const size_t OFF_X1  = 69206016;
  const size_t OFF_CSQ = 71303168;
  const size_t OFF_PD  = 71565312;
  const size_t OFF_PI  = 71827456;
  const size_t NEED    = 72089600;   // proven to fit in round 2
  if (ws_size < NEED) return;

  _Float16* c0 = (_Float16*)(ws + OFF_C0);
  _Float16* c1 = (_Float16*)(ws + OFF_C1);
  _Float16* x0 = (_Float16*)(ws + OFF_X0);
  _Float16* x1 = (_Float16*)(ws + OFF_X1);
  float* c_sq   = (float*)(ws + OFF_CSQ);
  float* part_d = (float*)(ws + OFF_PD);
  int*   part_i = (int*)(ws + OFF_PI);

  split_kernel<<<16384, 256, 0, stream>>>(cent, c0, c1, 65536 * 256 / 4);
  split_kernel<<<1024, 256, 0, stream>>>(x, x0, x1, 4096 * 256 / 4);
  csq_kernel<<<16384, 256, 0, stream>>>(cent, c_sq);
  mfma_dist_kernel<<<dim3(32, 16), 256, 0, stream>>>(x0, x1, c0, c1, c_sq, part_d, part_i);
  finalize_rescore<<<1024, 256, 0, stream>>>(part_i, x, cent, c_sq, out);
}

// Round 5
// 732.318 us; speedup vs baseline: 2.8404x; 1.0605x over previous
//
#include <hip/hip_runtime.h>
#include <hip/hip_bf16.h>
#include <math.h>

// B=4096 queries, D=256, K=65536 centroids (f32).
// dists[b,k] = ||c_k||^2 - 2 x_b.c_k ; codes=argmin ; out0=centroids[codes], out1=codes.
// Round 5: round-2's exact f16x2-split 3-term MFMA kernel (BK=32) with doubled grid:
// KCHUNK=2048, NKC=32 -> 1024 blocks = 4 blocks/CU (was 2). Same total staged bytes.
// part_d removed (finalize rescores exactly from part_i) to keep ws at proven size.

#define DDIM 256
#define NKC 32
#define KCHUNK 2048
#define F16_MINN 6.103515625e-5f

typedef __attribute__((ext_vector_type(8))) _Float16 half8;
typedef __attribute__((ext_vector_type(4))) _Float16 half4;
typedef __attribute__((ext_vector_type(4))) float f32x4;

__device__ __forceinline__ void gl_lds16(const void* g, void* l) {
  __builtin_amdgcn_global_load_lds((const __attribute__((address_space(1))) void*)g,
                                   (__attribute__((address_space(3))) void*)l, 16, 0, 0);
}

// ---------------- split: f32 -> (h0, h1*2048) f16 pair ----------------
__global__ __launch_bounds__(256) void split_kernel(const float* __restrict__ in,
                                                    _Float16* __restrict__ o0,
                                                    _Float16* __restrict__ o1, int n4) {
  int i = blockIdx.x * 256 + threadIdx.x;
  if (i >= n4) return;
  float4 v = ((const float4*)in)[i];
  float vv[4] = {v.x, v.y, v.z, v.w};
  half4 h0, h1;
#pragma unroll
  for (int e = 0; e < 4; ++e) {
    float x = vv[e];
    _Float16 a = (fabsf(x) < F16_MINN) ? (_Float16)0.f : (_Float16)x;
    float r = (x - (float)a) * 2048.0f;   // exact: cvt + Sterbenz sub + pow2 scale
    h0[e] = a;
    h1[e] = (_Float16)r;
  }
  *(half4*)(o0 + (size_t)i * 4) = h0;
  *(half4*)(o1 + (size_t)i * 4) = h1;
}

// ---------------- c_sq[k] = sum_d centroids[k][d]^2 (exact f32) ----------------
__global__ __launch_bounds__(256) void csq_kernel(const float* __restrict__ cent,
                                                  float* __restrict__ c_sq) {
  int gtid = blockIdx.x * 256 + threadIdx.x;
  int c = gtid >> 6;
  int lane = threadIdx.x & 63;
  float4 v = ((const float4*)(cent + (size_t)c * DDIM))[lane];
  float s = v.x * v.x + v.y * v.y + v.z * v.z + v.w * v.w;
#pragma unroll
  for (int off = 32; off > 0; off >>= 1) s += __shfl_down(s, off, 64);
  if (lane == 0) c_sq[c] = s;
}

// ---------------- MFMA distance + per-chunk argmin, BK=32, 4 blocks/CU ----------------
// Grid (32, 32). Block: 128 queries x 2048 centroids (ct=16 subtiles of 128).
// LDS per split: [8 subtiles s][4 quads q][16 rows r][8 f16] (quad-major: frag
// ds_read_b128 2-way-bank (free), staging lane-contiguous for global_load_lds).
__global__ __launch_bounds__(256, 2) void mfma_dist_kernel(
    const _Float16* __restrict__ x0, const _Float16* __restrict__ x1,
    const _Float16* __restrict__ c0, const _Float16* __restrict__ c1,
    const float* __restrict__ c_sq, int* __restrict__ part_i) {
  __shared__ __align__(16) _Float16 As0[4096], As1[4096], Bs0[4096], Bs1[4096];
  __shared__ float rd[2][128];
  __shared__ int   ri[2][128];

  const int qb = blockIdx.x, kc = blockIdx.y;
  const int tid = (int)threadIdx.x;
  const int lane = tid & 63, w = tid >> 6;
  const int mh = w >> 1, nh = w & 1;          // wave quadrant of the 128x128 tile
  const int col = lane & 15, quad = lane >> 4;
  const int qrow0 = qb * 128;

  float bestd[4][4];
  int   besti[4][4];
#pragma unroll
  for (int mt = 0; mt < 4; ++mt)
#pragma unroll
    for (int rg = 0; rg < 4; ++rg) { bestd[mt][rg] = INFINITY; besti[mt][rg] = 0x7fffffff; }

  for (int ct = 0; ct < KCHUNK / 128; ++ct) {
    const int cbase = kc * KCHUNK + ct * 128;
    f32x4 hi[4][4], lo[4][4];
#pragma unroll
    for (int mt = 0; mt < 4; ++mt)
#pragma unroll
      for (int nt = 0; nt < 4; ++nt) { hi[mt][nt] = (f32x4)0.0f; lo[mt][nt] = (f32x4)0.0f; }

    for (int kt = 0; kt < 8; ++kt) {
      const int k0 = kt * 32;
      __syncthreads();  // previous tile's ds_reads drained
#pragma unroll
      for (int i = 0; i < 2; ++i) {
        int u = i * 256 + tid;            // 0..511
        int s = u >> 6, q = (u >> 4) & 3, r = u & 15;
        size_t arow = (size_t)(qrow0 + s * 16 + r) * DDIM + k0 + q * 8;
        size_t brow = (size_t)(cbase + s * 16 + r) * DDIM + k0 + q * 8;
        gl_lds16(x0 + arow, As0 + (size_t)u * 8);
        gl_lds16(x1 + arow, As1 + (size_t)u * 8);
        gl_lds16(c0 + brow, Bs0 + (size_t)u * 8);
        gl_lds16(c1 + brow, Bs1 + (size_t)u * 8);
      }
      __syncthreads();

      half8 b0f[4], b1f[4];
#pragma unroll
      for (int nt = 0; nt < 4; ++nt) {
        int off = (((nh * 4 + nt) * 4 + quad) * 16 + col) * 8;
        b0f[nt] = *(const half8*)(Bs0 + off);
        b1f[nt] = *(const half8*)(Bs1 + off);
      }
#pragma unroll
      for (int mt = 0; mt < 4; ++mt) {
        int off = (((mh * 4 + mt) * 4 + quad) * 16 + col) * 8;
        half8 a0f = *(const half8*)(As0 + off);
        half8 a1f = *(const half8*)(As1 + off);
#pragma unroll
        for (int nt = 0; nt < 4; ++nt) {
          hi[mt][nt] = __builtin_amdgcn_mfma_f32_16x16x32_f16(a0f, b0f[nt], hi[mt][nt], 0, 0, 0);
          lo[mt][nt] = __builtin_amdgcn_mfma_f32_16x16x32_f16(a0f, b1f[nt], lo[mt][nt], 0, 0, 0);
          lo[mt][nt] = __builtin_amdgcn_mfma_f32_16x16x32_f16(a1f, b0f[nt], lo[mt][nt], 0, 0, 0);
        }
      }
    }
    // fold 128-wide subtile into running argmin (C layout: row=quad*4+rg, col=lane&15)
#pragma unroll
    for (int nt = 0; nt < 4; ++nt) {
      int cidx = cbase + (nh * 4 + nt) * 16 + col;
      float cs = c_sq[cidx];
#pragma unroll
      for (int mt = 0; mt < 4; ++mt)
#pragma unroll
        for (int rg = 0; rg < 4; ++rg) {
          float dot = hi[mt][nt][rg] + lo[mt][nt][rg] * (1.0f / 2048.0f);
          float d = fmaf(-2.0f, dot, cs);
          if (d < bestd[mt][rg] || (d == bestd[mt][rg] && cidx < besti[mt][rg])) {
            bestd[mt][rg] = d; besti[mt][rg] = cidx;
          }
        }
    }
  }

  // reduce across the 16 col-lanes holding each row
#pragma unroll
  for (int mt = 0; mt < 4; ++mt)
#pragma unroll
    for (int rg = 0; rg < 4; ++rg) {
      float d = bestd[mt][rg]; int ix = besti[mt][rg];
#pragma unroll
      for (int off = 1; off < 16; off <<= 1) {
        float od = __shfl_xor(d, off, 64);
        int   oi = __shfl_xor(ix, off, 64);
        if (od < d || (od == d && oi < ix)) { d = od; ix = oi; }
      }
      if (col == 0) {
        int row = mh * 64 + mt * 16 + quad * 4 + rg;
        rd[nh][row] = d; ri[nh][row] = ix;
      }
    }
  __syncthreads();
  if (tid < 128) {
    float d0 = rd[0][tid]; int i0 = ri[0][tid];
    float d1 = rd[1][tid]; int i1 = ri[1][tid];
    if (d1 < d0 || (d1 == d0 && i1 < i0)) { i0 = i1; }
    part_i[(size_t)(qrow0 + tid) * NKC + kc] = i0;
  }
}

// ---------------- finalize: exact-f32 rescore of 32 chunk winners + gather ----------------
__global__ __launch_bounds__(256) void finalize_rescore(
    const int* __restrict__ part_i, const float* __restrict__ x,
    const float* __restrict__ cent, const float* __restrict__ c_sq,
    float* __restrict__ out) {
  int q = blockIdx.x * 4 + ((int)threadIdx.x >> 6);
  int lane = (int)threadIdx.x & 63;
  float4 xv = ((const float4*)x)[(size_t)q * 64 + lane];
  float bd = INFINITY; int bi = 0x7fffffff;
  for (int p = 0; p < NKC; ++p) {
    int idx = part_i[(size_t)q * NKC + p];
    float4 cv = ((const float4*)cent)[(size_t)idx * 64 + lane];
    float s = xv.x * cv.x + xv.y * cv.y + xv.z * cv.z + xv.w * cv.w;
#pragma unroll
    for (int off = 32; off > 0; off >>= 1) s += __shfl_down(s, off, 64);
    s = __shfl(s, 0, 64);
    float d = fmaf(-2.0f, s, c_sq[idx]);
    if (d < bd || (d == bd && idx < bi)) { bd = d; bi = idx; }
  }
  float4 v = ((const float4*)cent)[(size_t)bi * 64 + lane];
  ((float4*)out)[(size_t)q * 64 + lane] = v;
  if (lane == 0) out[(size_t)4096 * DDIM + q] = (float)bi;
}

extern "C" void kernel_launch(void* const* d_in, const int* in_sizes, int n_in,
                              void* d_out, int out_size, void* d_ws, size_t ws_size,
                              hipStream_t stream) {
  const float* x    = (const float*)d_in[1];   // [4096,256]
  const float* cent = (const float*)d_in[2];   // [65536,256]
  float* out = (float*)d_out;
  char* ws = (char*)d_ws;

  const size_t OFF_C0  = 0;          // 33,554,432
  const size_t OFF_C1  = 33554432;   // 33,554,432
  const size_t OFF_X0  = 67108864;   //  2,097,152
  const size_t OFF_X1  = 69206016;   //  2,097,152
  const size_t OFF_CSQ = 71303168;   //    262,144
  const size_t OFF_PI  = 71565312;   //    524,288  i32[4096][32]
  const size_t NEED    = 72089600;   // == round-2's proven-fitting size
  if (ws_size < NEED) return;

  _Float16* c0 = (_Float16*)(ws + OFF_C0);
  _Float16* c1 = (_Float16*)(ws + OFF_C1);
  _Float16* x0 = (_Float16*)(ws + OFF_X0);
  _Float16* x1 = (_Float16*)(ws + OFF_X1);
  float* c_sq   = (float*)(ws + OFF_CSQ);
  int*   part_i = (int*)(ws + OFF_PI);

  split_kernel<<<16384, 256, 0, stream>>>(cent, c0, c1, 65536 * 256 / 4);
  split_kernel<<<1024, 256, 0, stream>>>(x, x0, x1, 4096 * 256 / 4);
  csq_kernel<<<16384, 256, 0, stream>>>(cent, c_sq);
  mfma_dist_kernel<<<dim3(32, 32), 256, 0, stream>>>(x0, x1, c0, c1, c_sq, part_i);
  finalize_rescore<<<1024, 256, 0, stream>>>(part_i, x, cent, c_sq, out);
}

// Round 6
// 635.374 us; speedup vs baseline: 3.2738x; 1.1526x over previous
//
#include <hip/hip_runtime.h>
#include <hip/hip_bf16.h>
#include <math.h>

// B=4096 queries, D=256, K=65536 centroids (f32).
// dists[b,k] = ||c_k||^2 - 2 x_b.c_k ; codes=argmin ; out0=centroids[codes], out1=codes.
// Round 6: barrier-free K-loop. A-tile (64q x 256k, f16x2 splits) persistent in LDS
// (staged once); B-fragments loaded per-wave directly global->VGPR (no LDS, no
// __syncthreads in the hot loop -> compiler-pipelined vmcnt). Same 3-term f16-split
// math as validated rounds 2/4/5; exact f32 rescore of per-strip winners.

#define DDIM 256
#define NST 8          // strips (chunk winners to rescore)
#define STSZ 8192      // centroids per strip
#define F16_MINN 6.103515625e-5f

typedef __attribute__((ext_vector_type(8))) _Float16 half8;
typedef __attribute__((ext_vector_type(4))) _Float16 half4;
typedef __attribute__((ext_vector_type(4))) float f32x4;

__device__ __forceinline__ void gl_lds16(const void* g, void* l) {
  __builtin_amdgcn_global_load_lds((const __attribute__((address_space(1))) void*)g,
                                   (__attribute__((address_space(3))) void*)l, 16, 0, 0);
}

// ---------------- split: f32 -> (h0, h1*2048) f16 pair ----------------
__global__ __launch_bounds__(256) void split_kernel(const float* __restrict__ in,
                                                    _Float16* __restrict__ o0,
                                                    _Float16* __restrict__ o1, int n4) {
  int i = blockIdx.x * 256 + threadIdx.x;
  if (i >= n4) return;
  float4 v = ((const float4*)in)[i];
  float vv[4] = {v.x, v.y, v.z, v.w};
  half4 h0, h1;
#pragma unroll
  for (int e = 0; e < 4; ++e) {
    float x = vv[e];
    _Float16 a = (fabsf(x) < F16_MINN) ? (_Float16)0.f : (_Float16)x;
    float r = (x - (float)a) * 2048.0f;   // exact: cvt + Sterbenz sub + pow2 scale
    h0[e] = a;
    h1[e] = (_Float16)r;
  }
  *(half4*)(o0 + (size_t)i * 4) = h0;
  *(half4*)(o1 + (size_t)i * 4) = h1;
}

// ---------------- c_sq[k] = sum_d centroids[k][d]^2 (exact f32) ----------------
__global__ __launch_bounds__(256) void csq_kernel(const float* __restrict__ cent,
                                                  float* __restrict__ c_sq) {
  int gtid = blockIdx.x * 256 + threadIdx.x;
  int c = gtid >> 6;
  int lane = threadIdx.x & 63;
  float4 v = ((const float4*)(cent + (size_t)c * DDIM))[lane];
  float s = v.x * v.x + v.y * v.y + v.z * v.z + v.w * v.w;
#pragma unroll
  for (int off = 32; off > 0; off >>= 1) s += __shfl_down(s, off, 64);
  if (lane == 0) c_sq[c] = s;
}

// ---------------- MFMA distance + per-strip argmin (barrier-free hot loop) ----------
// Grid (64 qb, 8 strips). Block: 64 queries x 8192 centroids.
// Each wave owns a 64-c slice of each 256-c subtile; full 64q rows (wave tile 64x64).
// A LDS layout: [kt 8][quad 4][row 64][8 halfs] per split (frag-read pattern has
// measured-zero bank conflicts in rounds 2-5).
__global__ __launch_bounds__(256, 2) void mfma_dist_kernel(
    const _Float16* __restrict__ x0, const _Float16* __restrict__ x1,
    const _Float16* __restrict__ c0, const _Float16* __restrict__ c1,
    const float* __restrict__ c_sq, int* __restrict__ part_i) {
  __shared__ __align__(16) _Float16 As0[16384], As1[16384];
  __shared__ float rd[4][64];
  __shared__ int   ri[4][64];

  const int qb = blockIdx.x, kc = blockIdx.y;
  const int tid = (int)threadIdx.x;
  const int lane = tid & 63, w = tid >> 6;
  const int col = lane & 15, quad = lane >> 4;
  const int qrow0 = qb * 64;

  // ---- stage A once: 64 rows x 256 k, both splits ----
#pragma unroll
  for (int i = 0; i < 8; ++i) {
    int u = i * 256 + tid;                 // 16B-chunk id 0..2047
    int kt = u >> 8, q = (u >> 6) & 3, r = u & 63;
    size_t src = (size_t)(qrow0 + r) * DDIM + kt * 32 + q * 8;
    gl_lds16(x0 + src, As0 + (size_t)u * 8);
    gl_lds16(x1 + src, As1 + (size_t)u * 8);
  }
  __syncthreads();   // the only barrier before the epilogue

  float bestd[4][4];
  int   besti[4][4];
#pragma unroll
  for (int mt = 0; mt < 4; ++mt)
#pragma unroll
    for (int rg = 0; rg < 4; ++rg) { bestd[mt][rg] = INFINITY; besti[mt][rg] = 0x7fffffff; }

  const int cw0 = kc * STSZ + w * 64;      // this wave's c-base in subtile 0

  for (int ct = 0; ct < STSZ / 256; ++ct) {
    const int cbase = cw0 + ct * 256;      // wave-private 64-c slice base
    f32x4 hi[4][4], lo[4][4];
#pragma unroll
    for (int mt = 0; mt < 4; ++mt)
#pragma unroll
      for (int nt = 0; nt < 4; ++nt) { hi[mt][nt] = (f32x4)0.0f; lo[mt][nt] = (f32x4)0.0f; }

#pragma unroll 2
    for (int kt = 0; kt < 8; ++kt) {
      const int k0 = kt * 32;
      half8 b0f[4], b1f[4];
#pragma unroll
      for (int nt = 0; nt < 4; ++nt) {
        size_t boff = (size_t)(cbase + nt * 16 + col) * DDIM + k0 + quad * 8;
        b0f[nt] = *(const half8*)(c0 + boff);   // global->VGPR, quad-lanes share 64B line
        b1f[nt] = *(const half8*)(c1 + boff);
      }
#pragma unroll
      for (int mt = 0; mt < 4; ++mt) {
        int aoff = (((kt * 4 + quad) * 64) + mt * 16 + col) * 8;
        half8 a0f = *(const half8*)(As0 + aoff);
        half8 a1f = *(const half8*)(As1 + aoff);
#pragma unroll
        for (int nt = 0; nt < 4; ++nt) {
          hi[mt][nt] = __builtin_amdgcn_mfma_f32_16x16x32_f16(a0f, b0f[nt], hi[mt][nt], 0, 0, 0);
          lo[mt][nt] = __builtin_amdgcn_mfma_f32_16x16x32_f16(a0f, b1f[nt], lo[mt][nt], 0, 0, 0);
          lo[mt][nt] = __builtin_amdgcn_mfma_f32_16x16x32_f16(a1f, b0f[nt], lo[mt][nt], 0, 0, 0);
        }
      }
    }
    // fold this 64-c slice into running argmin (C layout: row=quad*4+rg, col=lane&15)
#pragma unroll
    for (int nt = 0; nt < 4; ++nt) {
      int cidx = cbase + nt * 16 + col;
      float cs = c_sq[cidx];
#pragma unroll
      for (int mt = 0; mt < 4; ++mt)
#pragma unroll
        for (int rg = 0; rg < 4; ++rg) {
          float dot = hi[mt][nt][rg] + lo[mt][nt][rg] * (1.0f / 2048.0f);
          float d = fmaf(-2.0f, dot, cs);
          if (d < bestd[mt][rg] || (d == bestd[mt][rg] && cidx < besti[mt][rg])) {
            bestd[mt][rg] = d; besti[mt][rg] = cidx;
          }
        }
    }
  }

  // reduce across the 16 col-lanes (xor bits 0..3 stay within the 16-lane group)
#pragma unroll
  for (int mt = 0; mt < 4; ++mt)
#pragma unroll
    for (int rg = 0; rg < 4; ++rg) {
      float d = bestd[mt][rg]; int ix = besti[mt][rg];
#pragma unroll
      for (int off = 1; off < 16; off <<= 1) {
        float od = __shfl_xor(d, off, 64);
        int   oi = __shfl_xor(ix, off, 64);
        if (od < d || (od == d && oi < ix)) { d = od; ix = oi; }
      }
      if (col == 0) {
        int row = mt * 16 + quad * 4 + rg;   // local q-row 0..63
        rd[w][row] = d; ri[w][row] = ix;
      }
    }
  __syncthreads();
  if (tid < 64) {
    float d0 = rd[0][tid]; int i0 = ri[0][tid];
#pragma unroll
    for (int t = 1; t < 4; ++t) {
      float dd = rd[t][tid]; int ii = ri[t][tid];
      if (dd < d0 || (dd == d0 && ii < i0)) { d0 = dd; i0 = ii; }
    }
    part_i[(size_t)(qrow0 + tid) * NST + kc] = i0;
  }
}

// ---------------- finalize: exact-f32 rescore of 8 strip winners + gather ----------------
__global__ __launch_bounds__(256) void finalize_rescore(
    const int* __restrict__ part_i, const float* __restrict__ x,
    const float* __restrict__ cent, const float* __restrict__ c_sq,
    float* __restrict__ out) {
  int q = blockIdx.x * 4 + ((int)threadIdx.x >> 6);
  int lane = (int)threadIdx.x & 63;
  float4 xv = ((const float4*)x)[(size_t)q * 64 + lane];
  float bd = INFINITY; int bi = 0x7fffffff;
  for (int p = 0; p < NST; ++p) {
    int idx = part_i[(size_t)q * NST + p];
    float4 cv = ((const float4*)cent)[(size_t)idx * 64 + lane];
    float s = xv.x * cv.x + xv.y * cv.y + xv.z * cv.z + xv.w * cv.w;
#pragma unroll
    for (int off = 32; off > 0; off >>= 1) s += __shfl_down(s, off, 64);
    s = __shfl(s, 0, 64);
    float d = fmaf(-2.0f, s, c_sq[idx]);
    if (d < bd || (d == bd && idx < bi)) { bd = d; bi = idx; }
  }
  float4 v = ((const float4*)cent)[(size_t)bi * 64 + lane];
  ((float4*)out)[(size_t)q * 64 + lane] = v;
  if (lane == 0) out[(size_t)4096 * DDIM + q] = (float)bi;
}

extern "C" void kernel_launch(void* const* d_in, const int* in_sizes, int n_in,
                              void* d_out, int out_size, void* d_ws, size_t ws_size,
                              hipStream_t stream) {
  const float* x    = (const float*)d_in[1];   // [4096,256]
  const float* cent = (const float*)d_in[2];   // [65536,256]
  float* out = (float*)d_out;
  char* ws = (char*)d_ws;

  const size_t OFF_C0  = 0;          // 33,554,432
  const size_t OFF_C1  = 33554432;   // 33,554,432
  const size_t OFF_X0  = 67108864;   //  2,097,152
  const size_t OFF_X1  = 69206016;   //  2,097,152
  const size_t OFF_CSQ = 71303168;   //    262,144
  const size_t OFF_PI  = 71565312;   //    131,072  i32[4096][8]
  const size_t NEED    = 72089600;   // == round-2's proven-fitting size
  if (ws_size < NEED) return;

  _Float16* c0 = (_Float16*)(ws + OFF_C0);
  _Float16* c1 = (_Float16*)(ws + OFF_C1);
  _Float16* x0 = (_Float16*)(ws + OFF_X0);
  _Float16* x1 = (_Float16*)(ws + OFF_X1);
  float* c_sq   = (float*)(ws + OFF_CSQ);
  int*   part_i = (int*)(ws + OFF_PI);

  split_kernel<<<16384, 256, 0, stream>>>(cent, c0, c1, 65536 * 256 / 4);
  split_kernel<<<1024, 256, 0, stream>>>(x, x0, x1, 4096 * 256 / 4);
  csq_kernel<<<16384, 256, 0, stream>>>(cent, c_sq);
  mfma_dist_kernel<<<dim3(64, 8), 256, 0, stream>>>(x0, x1, c0, c1, c_sq, part_i);
  finalize_rescore<<<1024, 256, 0, stream>>>(part_i, x, cent, c_sq, out);
}

// Round 7
// 507.352 us; speedup vs baseline: 4.0999x; 1.2523x over previous
//
#include <hip/hip_runtime.h>
#include <hip/hip_bf16.h>
#include <math.h>

// B=4096 queries, D=256, K=65536 centroids (f32).
// dists[b,k] = ||c_k||^2 - 2 x_b.c_k ; codes=argmin ; out0=centroids[codes], out1=codes.
// Round 7: q-tile 128 (A f16x2 splits persistent in 131 KB LDS, staged once),
// 512-thread blocks / 8 waves, each wave owns a 128q x 32c slice -> B global reads
// halved vs round 6 (2.15 GB total), acc stays 128 regs -> 2 waves/SIMD.
// Barrier-free hot loop; same validated 3-term f16-split math + exact f32 rescore.

#define DDIM 256
#define NST 8          // strips
#define STSZ 8192      // centroids per strip
#define QTILE 128
#define F16_MINN 6.103515625e-5f

typedef __attribute__((ext_vector_type(8))) _Float16 half8;
typedef __attribute__((ext_vector_type(4))) _Float16 half4;
typedef __attribute__((ext_vector_type(4))) float f32x4;

__device__ __forceinline__ void gl_lds16(const void* g, void* l) {
  __builtin_amdgcn_global_load_lds((const __attribute__((address_space(1))) void*)g,
                                   (__attribute__((address_space(3))) void*)l, 16, 0, 0);
}

// ---------------- split: f32 -> (h0, h1*2048) f16 pair ----------------
__global__ __launch_bounds__(256) void split_kernel(const float* __restrict__ in,
                                                    _Float16* __restrict__ o0,
                                                    _Float16* __restrict__ o1, int n4) {
  int i = blockIdx.x * 256 + threadIdx.x;
  if (i >= n4) return;
  float4 v = ((const float4*)in)[i];
  float vv[4] = {v.x, v.y, v.z, v.w};
  half4 h0, h1;
#pragma unroll
  for (int e = 0; e < 4; ++e) {
    float x = vv[e];
    _Float16 a = (fabsf(x) < F16_MINN) ? (_Float16)0.f : (_Float16)x;
    float r = (x - (float)a) * 2048.0f;   // exact: cvt + Sterbenz sub + pow2 scale
    h0[e] = a;
    h1[e] = (_Float16)r;
  }
  *(half4*)(o0 + (size_t)i * 4) = h0;
  *(half4*)(o1 + (size_t)i * 4) = h1;
}

// ---------------- c_sq[k] = sum_d centroids[k][d]^2 (exact f32) ----------------
__global__ __launch_bounds__(256) void csq_kernel(const float* __restrict__ cent,
                                                  float* __restrict__ c_sq) {
  int gtid = blockIdx.x * 256 + threadIdx.x;
  int c = gtid >> 6;
  int lane = threadIdx.x & 63;
  float4 v = ((const float4*)(cent + (size_t)c * DDIM))[lane];
  float s = v.x * v.x + v.y * v.y + v.z * v.z + v.w * v.w;
#pragma unroll
  for (int off = 32; off > 0; off >>= 1) s += __shfl_down(s, off, 64);
  if (lane == 0) c_sq[c] = s;
}

// ---------------- MFMA distance + per-strip argmin ----------------
// Grid (32 qb, 8 strips). Block: 512 threads (8 waves), 128 queries x 8192 centroids.
// Wave w owns c-slice [w*32, w*32+32) of each 256-c subtile, all 128 q-rows.
// A LDS layout per split: [kt 8][quad 4][row 128][8 halfs] (frag reads 2-way-bank, free).
__global__ __launch_bounds__(512, 2) void mfma_dist_kernel(
    const _Float16* __restrict__ x0, const _Float16* __restrict__ x1,
    const _Float16* __restrict__ c0, const _Float16* __restrict__ c1,
    const float* __restrict__ c_sq, int* __restrict__ part_i) {
  __shared__ __align__(16) _Float16 As0[32768], As1[32768];   // 64 KiB each
  __shared__ float rd[8][QTILE];
  __shared__ int   ri[8][QTILE];

  const int qb = blockIdx.x, kc = blockIdx.y;
  const int tid = (int)threadIdx.x;
  const int lane = tid & 63, w = tid >> 6;    // 8 waves
  const int col = lane & 15, quad = lane >> 4;
  const int qrow0 = qb * QTILE;

  // ---- stage A once: 128 rows x 256 k, both splits (4096 chunks of 16 B per split) ----
#pragma unroll
  for (int i = 0; i < 8; ++i) {
    int u = i * 512 + tid;                 // 0..4095
    int kt = u >> 9, q = (u >> 7) & 3, r = u & 127;
    size_t src = (size_t)(qrow0 + r) * DDIM + kt * 32 + q * 8;
    gl_lds16(x0 + src, As0 + (size_t)u * 8);
    gl_lds16(x1 + src, As1 + (size_t)u * 8);
  }
  __syncthreads();   // the only barrier before the epilogue

  float bestd[8][4];
  int   besti[8][4];
#pragma unroll
  for (int mt = 0; mt < 8; ++mt)
#pragma unroll
    for (int rg = 0; rg < 4; ++rg) { bestd[mt][rg] = INFINITY; besti[mt][rg] = 0x7fffffff; }

  const int cw0 = kc * STSZ + w * 32;      // this wave's c-base in subtile 0

  for (int ct = 0; ct < STSZ / 256; ++ct) {
    const int cbase = cw0 + ct * 256;      // wave-private 32-c slice base
    f32x4 hi[8][2], lo[8][2];
#pragma unroll
    for (int mt = 0; mt < 8; ++mt)
#pragma unroll
      for (int nt = 0; nt < 2; ++nt) { hi[mt][nt] = (f32x4)0.0f; lo[mt][nt] = (f32x4)0.0f; }

#pragma unroll 2
    for (int kt = 0; kt < 8; ++kt) {
      const int k0 = kt * 32;
      half8 b0f[2], b1f[2];
#pragma unroll
      for (int nt = 0; nt < 2; ++nt) {
        size_t boff = (size_t)(cbase + nt * 16 + col) * DDIM + k0 + quad * 8;
        b0f[nt] = *(const half8*)(c0 + boff);   // global->VGPR, quads share 64B line
        b1f[nt] = *(const half8*)(c1 + boff);
      }
#pragma unroll
      for (int mt = 0; mt < 8; ++mt) {
        int aoff = (((kt * 4 + quad) * QTILE) + mt * 16 + col) * 8;
        half8 a0f = *(const half8*)(As0 + aoff);
        half8 a1f = *(const half8*)(As1 + aoff);
#pragma unroll
        for (int nt = 0; nt < 2; ++nt) {
          hi[mt][nt] = __builtin_amdgcn_mfma_f32_16x16x32_f16(a0f, b0f[nt], hi[mt][nt], 0, 0, 0);
          lo[mt][nt] = __builtin_amdgcn_mfma_f32_16x16x32_f16(a0f, b1f[nt], lo[mt][nt], 0, 0, 0);
          lo[mt][nt] = __builtin_amdgcn_mfma_f32_16x16x32_f16(a1f, b0f[nt], lo[mt][nt], 0, 0, 0);
        }
      }
    }
    // fold this 32-c slice into running argmin (C layout: row=quad*4+rg, col=lane&15)
#pragma unroll
    for (int nt = 0; nt < 2; ++nt) {
      int cidx = cbase + nt * 16 + col;
      float cs = c_sq[cidx];
#pragma unroll
      for (int mt = 0; mt < 8; ++mt)
#pragma unroll
        for (int rg = 0; rg < 4; ++rg) {
          float dot = hi[mt][nt][rg] + lo[mt][nt][rg] * (1.0f / 2048.0f);
          float d = fmaf(-2.0f, dot, cs);
          if (d < bestd[mt][rg] || (d == bestd[mt][rg] && cidx < besti[mt][rg])) {
            bestd[mt][rg] = d; besti[mt][rg] = cidx;
          }
        }
    }
  }

  // reduce across the 16 col-lanes (xor bits 0..3 stay within the 16-lane group)
#pragma unroll
  for (int mt = 0; mt < 8; ++mt)
#pragma unroll
    for (int rg = 0; rg < 4; ++rg) {
      float d = bestd[mt][rg]; int ix = besti[mt][rg];
#pragma unroll
      for (int off = 1; off < 16; off <<= 1) {
        float od = __shfl_xor(d, off, 64);
        int   oi = __shfl_xor(ix, off, 64);
        if (od < d || (od == d && oi < ix)) { d = od; ix = oi; }
      }
      if (col == 0) {
        int row = mt * 16 + quad * 4 + rg;   // local q-row 0..127
        rd[w][row] = d; ri[w][row] = ix;
      }
    }
  __syncthreads();
  if (tid < QTILE) {
    float d0 = rd[0][tid]; int i0 = ri[0][tid];
#pragma unroll
    for (int t = 1; t < 8; ++t) {
      float dd = rd[t][tid]; int ii = ri[t][tid];
      if (dd < d0 || (dd == d0 && ii < i0)) { d0 = dd; i0 = ii; }
    }
    part_i[(size_t)(qrow0 + tid) * NST + kc] = i0;
  }
}

// ---------------- finalize: exact-f32 rescore of 8 strip winners + gather ----------------
__global__ __launch_bounds__(256) void finalize_rescore(
    const int* __restrict__ part_i, const float* __restrict__ x,
    const float* __restrict__ cent, const float* __restrict__ c_sq,
    float* __restrict__ out) {
  int q = blockIdx.x * 4 + ((int)threadIdx.x >> 6);
  int lane = (int)threadIdx.x & 63;
  float4 xv = ((const float4*)x)[(size_t)q * 64 + lane];
  float bd = INFINITY; int bi = 0x7fffffff;
  for (int p = 0; p < NST; ++p) {
    int idx = part_i[(size_t)q * NST + p];
    float4 cv = ((const float4*)cent)[(size_t)idx * 64 + lane];
    float s = xv.x * cv.x + xv.y * cv.y + xv.z * cv.z + xv.w * cv.w;
#pragma unroll
    for (int off = 32; off > 0; off >>= 1) s += __shfl_down(s, off, 64);
    s = __shfl(s, 0, 64);
    float d = fmaf(-2.0f, s, c_sq[idx]);
    if (d < bd || (d == bd && idx < bi)) { bd = d; bi = idx; }
  }
  float4 v = ((const float4*)cent)[(size_t)bi * 64 + lane];
  ((float4*)out)[(size_t)q * 64 + lane] = v;
  if (lane == 0) out[(size_t)4096 * DDIM + q] = (float)bi;
}

extern "C" void kernel_launch(void* const* d_in, const int* in_sizes, int n_in,
                              void* d_out, int out_size, void* d_ws, size_t ws_size,
                              hipStream_t stream) {
  const float* x    = (const float*)d_in[1];   // [4096,256]
  const float* cent = (const float*)d_in[2];   // [65536,256]
  float* out = (float*)d_out;
  char* ws = (char*)d_ws;

  const size_t OFF_C0  = 0;          // 33,554,432
  const size_t OFF_C1  = 33554432;   // 33,554,432
  const size_t OFF_X0  = 67108864;   //  2,097,152
  const size_t OFF_X1  = 69206016;   //  2,097,152
  const size_t OFF_CSQ = 71303168;   //    262,144
  const size_t OFF_PI  = 71565312;   //    131,072  i32[4096][8]
  const size_t NEED    = 72089600;   // == round-2's proven-fitting size
  if (ws_size < NEED) return;

  _Float16* c0 = (_Float16*)(ws + OFF_C0);
  _Float16* c1 = (_Float16*)(ws + OFF_C1);
  _Float16* x0 = (_Float16*)(ws + OFF_X0);
  _Float16* x1 = (_Float16*)(ws + OFF_X1);
  float* c_sq   = (float*)(ws + OFF_CSQ);
  int*   part_i = (int*)(ws + OFF_PI);

  split_kernel<<<16384, 256, 0, stream>>>(cent, c0, c1, 65536 * 256 / 4);
  split_kernel<<<1024, 256, 0, stream>>>(x, x0, x1, 4096 * 256 / 4);
  csq_kernel<<<16384, 256, 0, stream>>>(cent, c_sq);
  mfma_dist_kernel<<<dim3(32, 8), 512, 0, stream>>>(x0, x1, c0, c1, c_sq, part_i);
  finalize_rescore<<<1024, 256, 0, stream>>>(part_i, x, cent, c_sq, out);
}